// Round 1
// baseline (83.100 us; speedup 1.0000x reference)
//
#include <hip/hip_runtime.h>

typedef float f32x4 __attribute__((ext_vector_type(4)));
typedef short s16x8 __attribute__((ext_vector_type(8)));

#define M_DIM 32
#define N_DIM 8192
#define K_DIM 8192
#define NBLK (K_DIM / 16)   // 512 fp4 blocks along K

// float -> bf16 bits, round-to-nearest-even (data has no NaNs)
__device__ inline unsigned short f2bf(float f) {
    unsigned int u = __float_as_uint(f);
    u = (u + 0x7FFFu + ((u >> 16) & 1u)) >> 16;
    return (unsigned short)u;
}

// Nearest FP4 (e2m1) value; ties at the boundary go DOWN (matches
// jnp.searchsorted side='left': idx = count of bounds strictly < |x|).
__device__ inline float round_fp4(float x) {
    float a = fabsf(x);
    float g;
    if (a > 2.5f)        g = (a > 5.0f) ? 6.0f : ((a > 3.5f) ? 4.0f : 3.0f);
    else if (a > 1.25f)  g = (a > 1.75f) ? 2.0f : 1.5f;
    else                 g = (a > 0.75f) ? 1.0f : ((a > 0.25f) ? 0.5f : 0.0f);
    return copysignf(g, x);
}

// Saturating round-to-nearest-even cast to float8_e4m3fn, back to f32.
// v >= 0 here (it's amax/6/input_scale).
__device__ inline float cast_e4m3(float v) {
    v = fminf(v, 448.0f);
    if (v < 0.015625f) {                       // subnormal range, step 2^-9
        return rintf(v * 512.0f) * (1.0f / 512.0f);
    }
    int e; float m = frexpf(v, &e);            // m in [0.5, 1)
    return ldexpf(rintf(m * 16.0f) * 0.0625f, e);  // 4 significant bits
}

// ---------------------------------------------------------------------------
// Phase 1: NVFP4 fake-quant of x and pack directly into MFMA B-fragment
// layout (bf16). One thread per 16-element block.
// Packed layout: xpack[(kstep*64 + lane)*16 + t*8 + j] =
//   x_dq[m = t*16 + (lane&15)][k = kstep*32 + (lane>>4)*8 + j]
// ---------------------------------------------------------------------------
__global__ void quant_pack_x(const float* __restrict__ x,
                             const float* __restrict__ input_scale,
                             unsigned short* __restrict__ xpack) {
    int tid = blockIdx.x * blockDim.x + threadIdx.x;   // 16384 threads
    int m = tid >> 9;          // row 0..31
    int b = tid & 511;         // block along K
    const float is = input_scale[0];

    const float* xp = x + (size_t)m * K_DIM + b * 16;
    f32x4 l0 = *(const f32x4*)(xp);
    f32x4 l1 = *(const f32x4*)(xp + 4);
    f32x4 l2 = *(const f32x4*)(xp + 8);
    f32x4 l3 = *(const f32x4*)(xp + 12);
    float v[16];
    #pragma unroll
    for (int i = 0; i < 4; ++i) { v[i]=l0[i]; v[4+i]=l1[i]; v[8+i]=l2[i]; v[12+i]=l3[i]; }

    float amax = 0.f;
    #pragma unroll
    for (int i = 0; i < 16; ++i) amax = fmaxf(amax, fabsf(v[i]));

    float sf = cast_e4m3(amax / 6.0f / is);
    float scale = sf * is;

    int kstep = b >> 1;
    int t = m >> 4;
    int mrow = m & 15;
    unsigned short* base = xpack + (size_t)kstep * 64 * 16;
    #pragma unroll
    for (int i = 0; i < 16; ++i) {
        float q = 0.f;
        if (scale > 0.f) q = round_fp4(v[i] / scale) * scale;
        int g = ((b & 1) << 1) + (i >> 3);   // k-group 0..3 within kstep
        int lane = g * 16 + mrow;
        int j = i & 7;
        base[(size_t)lane * 16 + t * 8 + j] = f2bf(q);
    }
}

// ---------------------------------------------------------------------------
// Phase 2: out[32, 8192] = x_dq @ w_dq^T + bias.
// One block per 16 N-rows; 8 waves split K 8-ways; LDS reduce at the end.
// ---------------------------------------------------------------------------
__global__ __launch_bounds__(512) void gemm_kernel(
    const float* __restrict__ W,
    const float* __restrict__ wscale,
    const float* __restrict__ ws2p,
    const float* __restrict__ bias,
    const unsigned short* __restrict__ xpack,
    float* __restrict__ out)
{
    __shared__ float red[8][512];
    const int wave = threadIdx.x >> 6;
    const int lane = threadIdx.x & 63;
    const int lrow = lane & 15;   // A row (n) / B col (m) index
    const int lgrp = lane >> 4;   // k-group 0..3
    const int n0 = blockIdx.x * 16;
    const int n = n0 + lrow;
    const float ws2 = ws2p[0];

    const int k_begin = wave * (K_DIM / 8);   // 1024 per wave
    const int ksteps = (K_DIM / 8) / 32;      // 32

    const float* wrow = W + (size_t)n * K_DIM + k_begin + lgrp * 8;
    const float* srow = wscale + (size_t)n * NBLK + (k_begin >> 4) + (lgrp >> 1);
    const unsigned short* xp = xpack + ((size_t)(k_begin >> 5) * 64 + lane) * 16;

    f32x4 acc0 = {0.f, 0.f, 0.f, 0.f};
    f32x4 acc1 = {0.f, 0.f, 0.f, 0.f};

    #pragma unroll 4
    for (int s = 0; s < ksteps; ++s) {
        f32x4 a0 = *(const f32x4*)(wrow);
        f32x4 a1 = *(const f32x4*)(wrow + 4);
        float sc = srow[2 * s] * ws2;          // per-16-block dequant scale
        s16x8 b0 = *(const s16x8*)(xp);
        s16x8 b1 = *(const s16x8*)(xp + 8);
        s16x8 af;
        #pragma unroll
        for (int j = 0; j < 4; ++j) af[j]     = (short)f2bf(a0[j] * sc);
        #pragma unroll
        for (int j = 0; j < 4; ++j) af[4 + j] = (short)f2bf(a1[j] * sc);
        acc0 = __builtin_amdgcn_mfma_f32_16x16x32_bf16(af, b0, acc0, 0, 0, 0);
        acc1 = __builtin_amdgcn_mfma_f32_16x16x32_bf16(af, b1, acc1, 0, 0, 0);
        wrow += 32;
        xp += 64 * 16;
    }

    float* my = red[wave];
    #pragma unroll
    for (int r = 0; r < 4; ++r) {
        my[lane * 8 + r]     = acc0[r];
        my[lane * 8 + 4 + r] = acc1[r];
    }
    __syncthreads();

    // 512 threads, 512 (n,m) outputs per block
    int i = threadIdx.x;
    float vsum = 0.f;
    #pragma unroll
    for (int w = 0; w < 8; ++w) vsum += red[w][i];
    int l = i >> 3, t = (i >> 2) & 1, r = i & 3;
    int nn = n0 + ((l >> 4) << 2) + r;     // C/D: row = (lane>>4)*4 + reg
    int mm = t * 16 + (l & 15);            // C/D: col = lane&15
    out[(size_t)mm * N_DIM + nn] = vsum + bias[nn];
}

extern "C" void kernel_launch(void* const* d_in, const int* in_sizes, int n_in,
                              void* d_out, int out_size, void* d_ws, size_t ws_size,
                              hipStream_t stream) {
    const float* x           = (const float*)d_in[0];
    const float* weight_fp4  = (const float*)d_in[1];
    const float* bias        = (const float*)d_in[2];
    const float* input_scale = (const float*)d_in[3];
    const float* wscale      = (const float*)d_in[4];
    const float* ws2         = (const float*)d_in[5];
    float* out = (float*)d_out;
    unsigned short* xpack = (unsigned short*)d_ws;   // 512 KB

    quant_pack_x<<<64, 256, 0, stream>>>(x, input_scale, xpack);
    gemm_kernel<<<512, 512, 0, stream>>>(weight_fp4, wscale, ws2, bias, xpack, out);
}